// Round 6
// baseline (8542.771 us; speedup 1.0000x reference)
//
#include <hip/hip_runtime.h>
#include <math.h>

#define T_LEN 4096
#define EDIM  256
#define HDIM  512
#define NTAGS 50
#define SENTW 0xFFFFFFFFu

__device__ __forceinline__ float sigm(float x) {
    return __builtin_amdgcn_rcpf(1.0f + __expf(-x));
}
__device__ __forceinline__ float tanh_fast(float x) {
    float e = __expf(2.0f * x);                       // x>>0 -> inf -> rcp=0 -> 1; x<<0 -> 0 -> -1
    return 1.0f - 2.0f * __builtin_amdgcn_rcpf(e + 1.0f);
}
__device__ __forceinline__ float u2f(unsigned u) { union { unsigned i; float f; } v; v.i = u; return v.f; }
__device__ __forceinline__ float rdlane(float v, int l) {
    union { float f; int i; } a, r;
    a.f = v;
    r.i = __builtin_amdgcn_readlane(a.i, l);   // SGPR broadcast, VALU-only
    return r.f;
}
// Agent-scope relaxed RMW poll: serviced at the device coherence point.
// Rounds 0-5 law: ONLY coherence-point ops observe cross-CU progress on this
// part; every L2-shortcut protocol (sc0 loads, no-scope swaps) lost.
__device__ __forceinline__ unsigned long long pollA(unsigned long long* p) {
    return __hip_atomic_fetch_or(p, 0ull, __ATOMIC_RELAXED, __HIP_MEMORY_SCOPE_AGENT);
}
__device__ __forceinline__ bool bad2(unsigned long long v) {
    return ((unsigned)v == SENTW) || ((unsigned)(v >> 32) == SENTW);
}

// ---------------------------------------------------------------------------
// Persistent bidirectional LSTM scan (f32), data-as-flag sync, SGPR-broadcast
// matvec. Round-6 = round-4 skeleton (proven fastest: 64 WGs round-robin,
// pure agent-scope sync, wave0 finalize, atomicExch publish) + three fixes:
//   (i)  WEIGHTS PINNED IN VGPRS: r4's VGPR_Count=112 proved the compiler
//        sank the 192 weight loads into the s-loop (re-fetched from L1/L2
//        every step, ~32 dependent VMEM loads on the critical path).
//        asm volatile("" : "+v"(x)) after each load makes the value opaque
//        -> reload illegal -> true register residency (~240 VGPRs).
//   (ii) CHUNKED h-matvec: the wave's 128 cols come from 8 producer blocks
//        (16 cols each). Process chunks as they arrive (ballot-gated),
//        overlapping re-poll RT of late producers with FMA of ready chunks.
//   (iii) EARLY POLL ISSUE: step s+1's first poll is issued right after the
//        barrier, BEFORE wave0's finalize, taking the finalize tail off the
//        poll lead time of the critical (wave0) chain.
// 64 WGs x 256 threads: blocks 0..31 forward, 32..63 backward.
// WG g owns hidden units [g*16,+16) => 64 gate rows. lane = row:
//   q = lane>>4 (gate i,f,g,o), u = lane&15, R = q*512 + g*16 + u.
// Wave wv owns cols [wv*128,+128) of W_hh, [wv*64,+64) of W_ih.
// Lane l polls the 8B word covering h cols {wv*128+2l, +1}; chunk j
// (lanes 8j..8j+7) is produced by block 8*wv + j.
// ---------------------------------------------------------------------------
__global__ __launch_bounds__(256, 1) void lstm_scan(
    const int* __restrict__ sent, const float* __restrict__ emb,
    const float* __restrict__ Wih_f, const float* __restrict__ Whh_f,
    const float* __restrict__ bih_f, const float* __restrict__ bhh_f,
    const float* __restrict__ Wih_b, const float* __restrict__ Whh_b,
    const float* __restrict__ bih_b, const float* __restrict__ bhh_b,
    float* hsf, float* hsb)
{
    const int tid  = threadIdx.x;
    const int lane = tid & 63;
    const int wv   = tid >> 6;          // wave id = column block
    const int dir  = blockIdx.x >> 5;
    const int g    = blockIdx.x & 31;

    const float* Wih = dir ? Wih_b : Wih_f;
    const float* Whh = dir ? Whh_b : Whh_f;
    const float* bih = dir ? bih_b : bih_f;
    const float* bhh = dir ? bhh_b : bhh_f;
    float* hs = dir ? hsb : hsf;

    const int q = lane >> 4;
    const int u = lane & 15;
    const int R = q * 512 + g * 16 + u;

    // W_hh cols [wv*128,+128) of row R -> 128 VGPRs (pinned).
    float wh[128];
    {
        const float* base = Whh + (size_t)R * HDIM + wv * 128;
        #pragma unroll
        for (int i = 0; i < 32; ++i) {
            float4 v = *(const float4*)(base + 4 * i);
            wh[4*i] = v.x; wh[4*i+1] = v.y; wh[4*i+2] = v.z; wh[4*i+3] = v.w;
        }
    }
    // W_ih cols [wv*64,+64) of row R -> 64 VGPRs (pinned).
    float wx[64];
    {
        const float* base = Wih + (size_t)R * EDIM + wv * 64;
        #pragma unroll
        for (int i = 0; i < 16; ++i) {
            float4 v = *(const float4*)(base + 4 * i);
            wx[4*i] = v.x; wx[4*i+1] = v.y; wx[4*i+2] = v.z; wx[4*i+3] = v.w;
        }
    }
    // Pin: value becomes asm-opaque -> compiler cannot re-load it from
    // memory inside the s-loop (defeats the load-sinking seen in r4).
    #pragma unroll
    for (int i = 0; i < 128; ++i) asm volatile("" : "+v"(wh[i]));
    #pragma unroll
    for (int i = 0; i < 64; ++i)  asm volatile("" : "+v"(wx[i]));

    const float bias = bih[R] + bhh[R];

    __shared__ float pl[2][256];
    float c_state = 0.0f;

    // Embedding value pipeline: lane holds emb[sent[t]][wv*64 + lane].
    float ecur;
    {
        int t0 = dir ? (T_LEN - 1) : 0;
        ecur = emb[(size_t)sent[t0] * EDIM + wv * 64 + lane];
    }

    unsigned long long* p = nullptr;   // poll addr/value for the CURRENT step,
    unsigned long long  v = 0;         // issued at the END of the previous one.

    for (int s = 0; s < T_LEN; ++s) {
        const int t = dir ? (T_LEN - 1 - s) : s;

        // Prefetch next step's embedding value (h-independent).
        float enext = 0.0f;
        if (s + 1 < T_LEN) {
            int tn = dir ? (t - 1) : (t + 1);
            enext = emb[(size_t)sent[tn] * EDIM + wv * 64 + lane];
        }

        // x partial: 64 SGPR-broadcast MACs over 4 independent accumulators
        // (runs under the in-flight early poll).
        float a0 = 0.f, a1 = 0.f, a2 = 0.f, a3 = 0.f;
        #pragma unroll
        for (int i = 0; i < 16; ++i) {
            a0 = fmaf(wx[4*i+0], rdlane(ecur, 4*i+0), a0);
            a1 = fmaf(wx[4*i+1], rdlane(ecur, 4*i+1), a1);
            a2 = fmaf(wx[4*i+2], rdlane(ecur, 4*i+2), a2);
            a3 = fmaf(wx[4*i+3], rdlane(ecur, 4*i+3), a3);
        }

        if (s > 0) {
            // Chunked consume: process each 16-col producer chunk as soon as
            // its 8 lanes are good; re-polls of late chunks overlap FMA of
            // ready ones. Single-outstanding per lane (r3: same-line polls
            // MSHR-merge, pipelining is useless).
            unsigned long long rdy = __ballot(!bad2(v));
            #pragma unroll
            for (int j = 0; j < 8; ++j) {
                const unsigned long long m = 0xFFull << (8 * j);
                while ((rdy & m) != m) {
                    if (bad2(v)) v = pollA(p);
                    rdy = __ballot(!bad2(v));
                }
                float h0 = u2f((unsigned)v);
                float h1 = u2f((unsigned)(v >> 32));
                #pragma unroll
                for (int e = 0; e < 8; ++e) {
                    const int ln = 8 * j + e;
                    if ((e & 1) == 0) {
                        a0 = fmaf(wh[16*j + 2*e],     rdlane(h0, ln), a0);
                        a1 = fmaf(wh[16*j + 2*e + 1], rdlane(h1, ln), a1);
                    } else {
                        a2 = fmaf(wh[16*j + 2*e],     rdlane(h0, ln), a2);
                        a3 = fmaf(wh[16*j + 2*e + 1], rdlane(h1, ln), a3);
                    }
                }
            }
        }

        pl[s & 1][wv * 64 + lane] = (a0 + a1) + (a2 + a3);
        __syncthreads();

        // Early issue of NEXT step's first poll (all waves), BEFORE the
        // finalize tail: next step (s+1) reads h[t] of the other blocks.
        unsigned long long* pn = nullptr;
        unsigned long long  vn = 0;
        if (s + 1 < T_LEN) {
            pn = (unsigned long long*)(hs + (size_t)t * HDIM + wv * 128) + lane;
            vn = pollA(pn);
        }

        // wave0 finalize (r4 structure), fast activations, one 16-lane
        // atomicExch wave-op = single 64B-line publish at the L3.
        if (wv == 0) {
            const float* pb = pl[s & 1];
            float tot = pb[lane] + pb[64 + lane] + pb[128 + lane] + pb[192 + lane] + bias;
            float gi = __shfl(tot, u,      64);
            float gf = __shfl(tot, u + 16, 64);
            float gg = __shfl(tot, u + 32, 64);
            float go = __shfl(tot, u + 48, 64);
            if (lane < 16) {
                float iv = sigm(gi), fv = sigm(gf);
                float gv = tanh_fast(gg), ov = sigm(go);
                c_state = fv * c_state + iv * gv;
                float h = ov * tanh_fast(c_state);
                __hip_atomic_exchange(hs + (size_t)t * HDIM + g * 16 + u, h,
                                      __ATOMIC_RELAXED, __HIP_MEMORY_SCOPE_AGENT);
            }
        }
        p = pn; v = vn;
        ecur = enext;
    }
}

// ---------------------------------------------------------------------------
// tag_space[t] = [hs_f[t] | hs_b[t]] @ W_out^T + b_out  (f32 out)
// ---------------------------------------------------------------------------
__global__ __launch_bounds__(256) void out_gemm(
    const float* __restrict__ hsf, const float* __restrict__ hsb,
    const float* __restrict__ Wout, const float* __restrict__ bout,
    float* __restrict__ out)
{
    const int t   = blockIdx.x;
    const int tid = threadIdx.x;
    __shared__ float h2[1024];

    if (tid < 128)
        *(float4*)(h2 + tid * 4) = *(const float4*)(hsf + (size_t)t * HDIM + tid * 4);
    else
        *(float4*)(h2 + 512 + (tid - 128) * 4) = *(const float4*)(hsb + (size_t)t * HDIM + (tid - 128) * 4);
    __syncthreads();

    const int wv = tid >> 6, lane = tid & 63;
    for (int tag = wv; tag < NTAGS; tag += 4) {
        const float4* wr = (const float4*)(Wout + (size_t)tag * (2 * HDIM));
        float p = 0.0f;
        #pragma unroll
        for (int c = lane; c < 256; c += 64) {
            float4 wv4 = wr[c];
            float4 hv  = *(const float4*)(h2 + c * 4);
            p += wv4.x * hv.x + wv4.y * hv.y + wv4.z * hv.z + wv4.w * hv.w;
        }
        p += __shfl_down(p, 32, 64);
        p += __shfl_down(p, 16, 64);
        p += __shfl_down(p, 8, 64);
        p += __shfl_down(p, 4, 64);
        p += __shfl_down(p, 2, 64);
        p += __shfl_down(p, 1, 64);
        if (lane == 0) out[(size_t)t * NTAGS + tag] = p + bout[tag];
    }
}

// ---------------------------------------------------------------------------
extern "C" void kernel_launch(void* const* d_in, const int* in_sizes, int n_in,
                              void* d_out, int out_size, void* d_ws, size_t ws_size,
                              hipStream_t stream)
{
    const int*   sent  = (const int*)d_in[0];
    const float* emb   = (const float*)d_in[1];
    const float* Wih_f = (const float*)d_in[2];
    const float* Whh_f = (const float*)d_in[3];
    const float* bih_f = (const float*)d_in[4];
    const float* bhh_f = (const float*)d_in[5];
    const float* Wih_b = (const float*)d_in[6];
    const float* Whh_b = (const float*)d_in[7];
    const float* bih_b = (const float*)d_in[8];
    const float* bhh_b = (const float*)d_in[9];
    const float* Wout  = (const float*)d_in[10];
    const float* bout  = (const float*)d_in[11];
    float* out = (float*)d_out;

    char* ws = (char*)d_ws;
    // Workspace: hsf [4096*512 f32] @ 0 (8 MiB), hsb @ 8 MiB. Both double as
    // sync flags: sentinel-fill with 0xFF (-NaN, never produced by o*tanh(c)).
    float* hsf = (float*)(ws);
    float* hsb = (float*)(ws + 8388608);
    hipMemsetAsync(ws, 0xFF, 16777216, stream);

    lstm_scan<<<64, 256, 0, stream>>>(sent, emb,
                                      Wih_f, Whh_f, bih_f, bhh_f,
                                      Wih_b, Whh_b, bih_b, bhh_b,
                                      hsf, hsb);
    out_gemm<<<T_LEN, 256, 0, stream>>>(hsf, hsb, Wout, bout, out);
}

// Round 7
// 6278.237 us; speedup vs baseline: 1.3607x; 1.3607x over previous
//
#include <hip/hip_runtime.h>
#include <math.h>

#define T_LEN 4096
#define EDIM  256
#define HDIM  512
#define NTAGS 50
#define SENTW 0xFFFFFFFFu

__device__ __forceinline__ float sigm(float x) {
    return __builtin_amdgcn_rcpf(1.0f + __expf(-x));
}
__device__ __forceinline__ float tanh_fast(float x) {
    float e = __expf(2.0f * x);                       // x>>0 -> inf -> rcp=0 -> 1; x<<0 -> 0 -> -1
    return 1.0f - 2.0f * __builtin_amdgcn_rcpf(e + 1.0f);
}
__device__ __forceinline__ float u2f(unsigned u) { union { unsigned i; float f; } v; v.i = u; return v.f; }
__device__ __forceinline__ float rdlane(float v, int l) {
    union { float f; int i; } a, r;
    a.f = v;
    r.i = __builtin_amdgcn_readlane(a.i, l);   // SGPR broadcast, VALU-only
    return r.f;
}
// Agent-scope relaxed RMW poll: serviced at the device coherence point.
// Rounds 0-6 law: ONLY coherence-point ops observe cross-CU progress on this
// part (every L2-shortcut protocol lost); tight per-lane spin beats any
// ballot/chunk restructure (r6); same-line poll pipelining MSHR-merges (r3).
__device__ __forceinline__ unsigned long long pollA(unsigned long long* p) {
    return __hip_atomic_fetch_or(p, 0ull, __ATOMIC_RELAXED, __HIP_MEMORY_SCOPE_AGENT);
}
__device__ __forceinline__ bool bad2(unsigned long long v) {
    return ((unsigned)v == SENTW) || ((unsigned)(v >> 32) == SENTW);
}

// ---------------------------------------------------------------------------
// Persistent bidirectional LSTM scan (f32), SGPR-broadcast matvec.
// Round-7 = round-4 byte-identical skeleton (proven 5.94 ms: 64 WGs round-
// robin, pure agent sync, tight spin, 4-chain FMA, wave0 finalize, atomicExch
// publish) + RING MAILBOX so sync lines are L3-HOT:
//   * r4's polls targeted hs[t] - a NEW 64B line every step (16MB stream),
//     always cold => every poll and every publish was HBM-class (~900cy).
//     FETCH_SIZE 166MB == poll traffic was the smoking gun.
//   * Now h is published into an 8-slot ring mailbox (slot = s&7, 512 f32 x
//     8 slots x 2 dirs = 32KB total). The 32 lines per slot are reused every
//     8 steps -> L3-resident -> publish visibility + poll RT drop to L3-hit
//     class. hs[] remains the archive for out_gemm, written with a plain
//     store OFF the critical path.
//   * ABA-safe ring reuse: producer resets its 64B of slot (s+4)&7 to the
//     sentinel each step. Inter-block drift is <=1 step (all-to-all consume
//     each step), so slot s+4's previous consumers (step s-3) are long done.
// 64 WGs x 256 threads: blocks 0..31 forward, 32..63 backward.
// WG g owns hidden units [g*16,+16) => 64 gate rows. lane = row:
//   q = lane>>4 (gate i,f,g,o), u = lane&15, R = q*512 + g*16 + u.
// Wave wv owns cols [wv*128,+128) of W_hh, [wv*64,+64) of W_ih; lane l polls
// the 8B mailbox word covering h cols {wv*128+2l, +1}.
// ---------------------------------------------------------------------------
__global__ __launch_bounds__(256, 1) void lstm_scan(
    const int* __restrict__ sent, const float* __restrict__ emb,
    const float* __restrict__ Wih_f, const float* __restrict__ Whh_f,
    const float* __restrict__ bih_f, const float* __restrict__ bhh_f,
    const float* __restrict__ Wih_b, const float* __restrict__ Whh_b,
    const float* __restrict__ bih_b, const float* __restrict__ bhh_b,
    float* hsf, float* hsb, float* mbf, float* mbb)
{
    const int tid  = threadIdx.x;
    const int lane = tid & 63;
    const int wv   = tid >> 6;          // wave id = column block
    const int dir  = blockIdx.x >> 5;
    const int g    = blockIdx.x & 31;

    const float* Wih = dir ? Wih_b : Wih_f;
    const float* Whh = dir ? Whh_b : Whh_f;
    const float* bih = dir ? bih_b : bih_f;
    const float* bhh = dir ? bhh_b : bhh_f;
    float* hs = dir ? hsb : hsf;
    float* mb = dir ? mbb : mbf;

    const int q = lane >> 4;
    const int u = lane & 15;
    const int R = q * 512 + g * 16 + u;

    // W_hh cols [wv*128,+128) of row R -> 128 VGPRs.
    float wh[128];
    {
        const float* base = Whh + (size_t)R * HDIM + wv * 128;
        #pragma unroll
        for (int i = 0; i < 32; ++i) {
            float4 v = *(const float4*)(base + 4 * i);
            wh[4*i] = v.x; wh[4*i+1] = v.y; wh[4*i+2] = v.z; wh[4*i+3] = v.w;
        }
    }
    // W_ih cols [wv*64,+64) of row R -> 64 VGPRs.
    float wx[64];
    {
        const float* base = Wih + (size_t)R * EDIM + wv * 64;
        #pragma unroll
        for (int i = 0; i < 16; ++i) {
            float4 v = *(const float4*)(base + 4 * i);
            wx[4*i] = v.x; wx[4*i+1] = v.y; wx[4*i+2] = v.z; wx[4*i+3] = v.w;
        }
    }
    const float bias = bih[R] + bhh[R];

    __shared__ float pl[2][256];
    float c_state = 0.0f;

    // Embedding value pipeline: lane holds emb[sent[t]][wv*64 + lane].
    float ecur;
    {
        int t0 = dir ? (T_LEN - 1) : 0;
        ecur = emb[(size_t)sent[t0] * EDIM + wv * 64 + lane];
    }

    for (int s = 0; s < T_LEN; ++s) {
        const int t = dir ? (T_LEN - 1 - s) : s;

        // Issue first poll sample ASAP so it flies under the x-matvec.
        // Target: ring slot (s-1)&7 (h of step s-1), L3-hot lines.
        unsigned long long* p = nullptr;
        unsigned long long v = 0;
        if (s > 0) {
            p = (unsigned long long*)(mb + ((s - 1) & 7) * 512 + wv * 128) + lane;
            v = pollA(p);
        }
        // Prefetch next step's embedding value (h-independent).
        float enext = 0.0f;
        if (s + 1 < T_LEN) {
            int tn = dir ? (t - 1) : (t + 1);
            enext = emb[(size_t)sent[tn] * EDIM + wv * 64 + lane];
        }

        // x partial: 64 SGPR-broadcast MACs over 4 independent accumulators
        // (hidden under the in-flight first poll).
        float a0 = 0.f, a1 = 0.f, a2 = 0.f, a3 = 0.f;
        #pragma unroll
        for (int i = 0; i < 16; ++i) {
            a0 = fmaf(wx[4*i+0], rdlane(ecur, 4*i+0), a0);
            a1 = fmaf(wx[4*i+1], rdlane(ecur, 4*i+1), a1);
            a2 = fmaf(wx[4*i+2], rdlane(ecur, 4*i+2), a2);
            a3 = fmaf(wx[4*i+3], rdlane(ecur, 4*i+3), a3);
        }

        if (s > 0) {
            // Tight single-outstanding spin (r4-proven; r6's chunking lost).
            while (bad2(v)) v = pollA(p);
            float h0 = u2f((unsigned)v);
            float h1 = u2f((unsigned)(v >> 32));
            // h partial: 128 SGPR-broadcast MACs, 4 chains.
            #pragma unroll
            for (int i = 0; i < 32; ++i) {
                a0 = fmaf(wh[4*i+0], rdlane(h0, 2*i+0), a0);
                a1 = fmaf(wh[4*i+1], rdlane(h1, 2*i+0), a1);
                a2 = fmaf(wh[4*i+2], rdlane(h0, 2*i+1), a2);
                a3 = fmaf(wh[4*i+3], rdlane(h1, 2*i+1), a3);
            }
        }

        pl[s & 1][wv * 64 + lane] = (a0 + a1) + (a2 + a3);
        __syncthreads();

        // wave0 finalize (r4 structure), fast activations.
        if (wv == 0) {
            const float* pb = pl[s & 1];
            float tot = pb[lane] + pb[64 + lane] + pb[128 + lane] + pb[192 + lane] + bias;
            float gi = __shfl(tot, u,      64);
            float gf = __shfl(tot, u + 16, 64);
            float gg = __shfl(tot, u + 32, 64);
            float go = __shfl(tot, u + 48, 64);
            if (lane < 16) {
                float iv = sigm(gi), fv = sigm(gf);
                float gv = tanh_fast(gg), ov = sigm(go);
                c_state = fv * c_state + iv * gv;
                float h = ov * tanh_fast(c_state);
                // (1) CRITICAL: publish into ring slot s&7 (L3-hot line,
                //     16-lane atomicExch wave-op = one 64B line at the TCC).
                __hip_atomic_exchange(mb + (s & 7) * 512 + g * 16 + u, h,
                                      __ATOMIC_RELAXED, __HIP_MEMORY_SCOPE_AGENT);
                // (2) archive for out_gemm (next dispatch) - plain store,
                //     off the critical path.
                hs[(size_t)t * HDIM + g * 16 + u] = h;
                // (3) re-arm ring slot (s+4)&7 with the sentinel (its step
                //     s-4 consumers finished at step s-3; drift <=1 => safe).
                __hip_atomic_store((unsigned*)mb + ((s + 4) & 7) * 512 + g * 16 + u,
                                   SENTW, __ATOMIC_RELAXED, __HIP_MEMORY_SCOPE_AGENT);
            }
        }
        ecur = enext;
    }
}

// ---------------------------------------------------------------------------
// tag_space[t] = [hs_f[t] | hs_b[t]] @ W_out^T + b_out  (f32 out)
// ---------------------------------------------------------------------------
__global__ __launch_bounds__(256) void out_gemm(
    const float* __restrict__ hsf, const float* __restrict__ hsb,
    const float* __restrict__ Wout, const float* __restrict__ bout,
    float* __restrict__ out)
{
    const int t   = blockIdx.x;
    const int tid = threadIdx.x;
    __shared__ float h2[1024];

    if (tid < 128)
        *(float4*)(h2 + tid * 4) = *(const float4*)(hsf + (size_t)t * HDIM + tid * 4);
    else
        *(float4*)(h2 + 512 + (tid - 128) * 4) = *(const float4*)(hsb + (size_t)t * HDIM + (tid - 128) * 4);
    __syncthreads();

    const int wv = tid >> 6, lane = tid & 63;
    for (int tag = wv; tag < NTAGS; tag += 4) {
        const float4* wr = (const float4*)(Wout + (size_t)tag * (2 * HDIM));
        float p = 0.0f;
        #pragma unroll
        for (int c = lane; c < 256; c += 64) {
            float4 wv4 = wr[c];
            float4 hv  = *(const float4*)(h2 + c * 4);
            p += wv4.x * hv.x + wv4.y * hv.y + wv4.z * hv.z + wv4.w * hv.w;
        }
        p += __shfl_down(p, 32, 64);
        p += __shfl_down(p, 16, 64);
        p += __shfl_down(p, 8, 64);
        p += __shfl_down(p, 4, 64);
        p += __shfl_down(p, 2, 64);
        p += __shfl_down(p, 1, 64);
        if (lane == 0) out[(size_t)t * NTAGS + tag] = p + bout[tag];
    }
}

// ---------------------------------------------------------------------------
extern "C" void kernel_launch(void* const* d_in, const int* in_sizes, int n_in,
                              void* d_out, int out_size, void* d_ws, size_t ws_size,
                              hipStream_t stream)
{
    const int*   sent  = (const int*)d_in[0];
    const float* emb   = (const float*)d_in[1];
    const float* Wih_f = (const float*)d_in[2];
    const float* Whh_f = (const float*)d_in[3];
    const float* bih_f = (const float*)d_in[4];
    const float* bhh_f = (const float*)d_in[5];
    const float* Wih_b = (const float*)d_in[6];
    const float* Whh_b = (const float*)d_in[7];
    const float* bih_b = (const float*)d_in[8];
    const float* bhh_b = (const float*)d_in[9];
    const float* Wout  = (const float*)d_in[10];
    const float* bout  = (const float*)d_in[11];
    float* out = (float*)d_out;

    char* ws = (char*)d_ws;
    // Workspace: hsf [4096*512 f32] @ 0 (8 MiB), hsb @ 8 MiB. Pure archives
    // now (fully written before out_gemm reads) -> no 16MB sentinel memset.
    float* hsf = (float*)(ws);
    float* hsb = (float*)(ws + 8388608);

    // Ring mailboxes: 8 slots x 512 f32 x 2 dirs = 32 KiB, sentinel-filled.
    // Prefer workspace tail; fall back to the tail of 'out' (lstm_scan only
    // touches it as mailbox; out_gemm fully rewrites out afterwards).
    float* mbf;
    if (ws_size >= 16777216 + 32768) mbf = (float*)(ws + 16777216);
    else                             mbf = (float*)((char*)d_out + out_size - 32768);
    float* mbb = mbf + 4096;
    hipMemsetAsync(mbf, 0xFF, 32768, stream);

    lstm_scan<<<64, 256, 0, stream>>>(sent, emb,
                                      Wih_f, Whh_f, bih_f, bhh_f,
                                      Wih_b, Whh_b, bih_b, bhh_b,
                                      hsf, hsb, mbf, mbb);
    out_gemm<<<T_LEN, 256, 0, stream>>>(hsf, hsb, Wout, bout, out);
}